// Round 1
// baseline (10158.975 us; speedup 1.0000x reference)
//
#include <hip/hip_runtime.h>

namespace {

constexpr int kB = 32;
constexpr int kT = 64;
constexpr int kH = 1024;
constexpr int kE = 1024;
constexpr int kV = 16000;
constexpr int kG = 4096;  // 4*H

__device__ __forceinline__ float sigmoid_f(float x) {
  return 1.0f / (1.0f + __expf(-x));
}

// ---------------- t=0 logits slice ----------------
__global__ void zero_t0_kernel(float* __restrict__ out) {
  int idx = blockIdx.x * blockDim.x + threadIdx.x;
  if (idx >= kB * kV) return;
  int b = idx / kV, v = idx % kV;
  out[(size_t)b * kT * kV + v] = 0.0f;
}

// JAX outer-index semantics: out[b, 0, output_ids[j, 0]] = 1 for ALL (b, j)
__global__ void ones_t0_kernel(const int* __restrict__ output_ids,
                               float* __restrict__ out) {
  int b = threadIdx.x >> 5;   // 0..31
  int j = threadIdx.x & 31;   // 0..31
  int id = output_ids[j * kT];  // output_ids[j][0]
  out[(size_t)b * kT * kV + id] = 1.0f;
}

// ---- proj: C[m, n] = emb[id(m), :] . W[n, :] + b0[n] + b1[n]
// m = t*B + b (time-major), id(m) = ids[b*T + t]. M rows, N=4096, K=1024.
// 128x128 tile, BK=16, 256 threads, 8x8 micro-tile (split 4+4 at +64 offset).
__global__ __launch_bounds__(256)
void proj_gather_gemm(const float* __restrict__ emb, const int* __restrict__ ids,
                      const float* __restrict__ W, const float* __restrict__ b0,
                      const float* __restrict__ b1, float* __restrict__ C, int M) {
  __shared__ alignas(16) float As[16][132];
  __shared__ alignas(16) float Ws[16][132];
  const int bm = blockIdx.x * 128;
  const int bn = blockIdx.y * 128;
  const int tid = threadIdx.x;
  const int tx = tid & 15;   // n group
  const int ty = tid >> 4;   // m group
  float acc[8][8] = {};
  for (int k0 = 0; k0 < kH; k0 += 16) {
#pragma unroll
    for (int p = 0; p < 2; ++p) {
      const int ff = tid + p * 256;  // 0..511
      const int r = ff >> 2;         // 0..127
      const int kc = ff & 3;
      const int m = bm + r;
      float4 av = make_float4(0.f, 0.f, 0.f, 0.f);
      if (m < M) {
        const int tt = m >> 5, bb = m & 31;
        const int id = ids[bb * kT + tt];
        av = *reinterpret_cast<const float4*>(&emb[(size_t)id * kE + k0 + kc * 4]);
      }
      As[kc * 4 + 0][r] = av.x; As[kc * 4 + 1][r] = av.y;
      As[kc * 4 + 2][r] = av.z; As[kc * 4 + 3][r] = av.w;
      const float4 wv =
          *reinterpret_cast<const float4*>(&W[(size_t)(bn + r) * kH + k0 + kc * 4]);
      Ws[kc * 4 + 0][r] = wv.x; Ws[kc * 4 + 1][r] = wv.y;
      Ws[kc * 4 + 2][r] = wv.z; Ws[kc * 4 + 3][r] = wv.w;
    }
    __syncthreads();
#pragma unroll
    for (int kk = 0; kk < 16; ++kk) {
      float a[8], w[8];
      *reinterpret_cast<float4*>(&a[0]) = *reinterpret_cast<const float4*>(&As[kk][ty * 4]);
      *reinterpret_cast<float4*>(&a[4]) = *reinterpret_cast<const float4*>(&As[kk][64 + ty * 4]);
      *reinterpret_cast<float4*>(&w[0]) = *reinterpret_cast<const float4*>(&Ws[kk][tx * 4]);
      *reinterpret_cast<float4*>(&w[4]) = *reinterpret_cast<const float4*>(&Ws[kk][64 + tx * 4]);
#pragma unroll
      for (int i = 0; i < 8; ++i)
#pragma unroll
        for (int j = 0; j < 8; ++j) acc[i][j] = fmaf(a[i], w[j], acc[i][j]);
    }
    __syncthreads();
  }
#pragma unroll
  for (int i = 0; i < 8; ++i) {
    const int m = bm + ty * 4 + (i >> 2) * 64 + (i & 3);
    if (m >= M) continue;
#pragma unroll
    for (int j = 0; j < 8; ++j) {
      const int n = bn + tx * 4 + (j >> 2) * 64 + (j & 3);
      C[(size_t)m * kG + n] = acc[i][j] + b0[n] + b1[n];
    }
  }
}

// ---- output GEMM: logits[b, s+1, v] = htop[s*B+b, :] . Wout[v, :] + bout[v]
__global__ __launch_bounds__(256)
void out_gemm(const float* __restrict__ A, const float* __restrict__ W,
              const float* __restrict__ bias, float* __restrict__ out) {
  constexpr int M = (kT - 1) * kB;  // 2016
  __shared__ alignas(16) float As[16][132];
  __shared__ alignas(16) float Ws[16][132];
  const int bm = blockIdx.x * 128;
  const int bn = blockIdx.y * 128;
  const int tid = threadIdx.x;
  const int tx = tid & 15;
  const int ty = tid >> 4;
  float acc[8][8] = {};
  for (int k0 = 0; k0 < kH; k0 += 16) {
#pragma unroll
    for (int p = 0; p < 2; ++p) {
      const int ff = tid + p * 256;
      const int r = ff >> 2;
      const int kc = ff & 3;
      const int m = bm + r;
      float4 av = make_float4(0.f, 0.f, 0.f, 0.f);
      if (m < M) av = *reinterpret_cast<const float4*>(&A[(size_t)m * kH + k0 + kc * 4]);
      As[kc * 4 + 0][r] = av.x; As[kc * 4 + 1][r] = av.y;
      As[kc * 4 + 2][r] = av.z; As[kc * 4 + 3][r] = av.w;
      const float4 wv =
          *reinterpret_cast<const float4*>(&W[(size_t)(bn + r) * kH + k0 + kc * 4]);
      Ws[kc * 4 + 0][r] = wv.x; Ws[kc * 4 + 1][r] = wv.y;
      Ws[kc * 4 + 2][r] = wv.z; Ws[kc * 4 + 3][r] = wv.w;
    }
    __syncthreads();
#pragma unroll
    for (int kk = 0; kk < 16; ++kk) {
      float a[8], w[8];
      *reinterpret_cast<float4*>(&a[0]) = *reinterpret_cast<const float4*>(&As[kk][ty * 4]);
      *reinterpret_cast<float4*>(&a[4]) = *reinterpret_cast<const float4*>(&As[kk][64 + ty * 4]);
      *reinterpret_cast<float4*>(&w[0]) = *reinterpret_cast<const float4*>(&Ws[kk][tx * 4]);
      *reinterpret_cast<float4*>(&w[4]) = *reinterpret_cast<const float4*>(&Ws[kk][64 + tx * 4]);
#pragma unroll
      for (int i = 0; i < 8; ++i)
#pragma unroll
        for (int j = 0; j < 8; ++j) acc[i][j] = fmaf(a[i], w[j], acc[i][j]);
    }
    __syncthreads();
  }
#pragma unroll
  for (int i = 0; i < 8; ++i) {
    const int m = bm + ty * 4 + (i >> 2) * 64 + (i & 3);
    if (m >= M) continue;
    const int s = m >> 5, bb = m & 31;
    float* orow = out + (size_t)bb * kT * kV + (size_t)(s + 1) * kV;
#pragma unroll
    for (int j = 0; j < 8; ++j) {
      const int n = bn + tx * 4 + (j >> 2) * 64 + (j & 3);
      orow[n] = acc[i][j] + bias[n];
    }
  }
}

// ---- fused LSTM cell: one (step, layer).
// Block handles 4 j-columns (all 4 gates, all 32 rows), grid = 256 blocks.
// Gates: g[m, q*H+j] = sum_k src[m,k]*W[q*H+j,k] (+ xproj or bias), then
// c_new = sig(f)*c + sig(i)*tanh(g); h_new = sig(o)*tanh(c_new).
// 128 threads: tm = tid&15 (m pair), tj = (tid>>4)&3 (j), kg = tid>>6 (K half).
template <bool IS_L1>
__global__ __launch_bounds__(128)
void lstm_cell(const float* __restrict__ h_in,   // (B,H) this layer's h_prev
               const float* __restrict__ x_in,   // L1: lower layer h_new
               const float* __restrict__ xproj,  // L0: precomputed x-part (pre-biased)
               const float* __restrict__ Wih,    // L1 only (4096,1024)
               const float* __restrict__ Whh,    // (4096,1024)
               const float* __restrict__ bih,    // L1 only
               const float* __restrict__ bhh,    // L1 only
               float* __restrict__ c_io,         // (B,H) in/out
               float* __restrict__ h_out,        // (B,H)
               float* __restrict__ h_top)        // optional copy
{
  __shared__ float Xs[64][33];
  __shared__ float Ws[64][17];
  __shared__ float Red[64][8];
  const int tid = threadIdx.x;
  const int tm = tid & 15;
  const int tj = (tid >> 4) & 3;
  const int kg = tid >> 6;
  const int j0 = blockIdx.x * 4;
  float acc[4][2] = {};  // [gate][m in pair]

  const int nph = IS_L1 ? 2 : 1;
  for (int ph = 0; ph < nph; ++ph) {
    const float* src = (ph == 0) ? h_in : x_in;
    const float* Wm = (ph == 0) ? Whh : Wih;
    for (int k0 = 0; k0 < kH; k0 += 64) {
#pragma unroll
      for (int i = 0; i < 16; ++i) {
        const int l = tid + i * 128;  // 0..2047
        const int m = l >> 6, kk = l & 63;
        Xs[kk][m] = src[m * kH + k0 + kk];
      }
#pragma unroll
      for (int i = 0; i < 8; ++i) {
        const int l = tid + i * 128;  // 0..1023
        const int r = l >> 6, kk = l & 63;
        const int q = r >> 2, jj = r & 3;
        Ws[kk][r] = Wm[(size_t)(q * kH + j0 + jj) * kH + k0 + kk];
      }
      __syncthreads();
#pragma unroll
      for (int kk2 = 0; kk2 < 32; ++kk2) {
        const int kk = kg * 32 + kk2;
        const float x0 = Xs[kk][2 * tm];
        const float x1 = Xs[kk][2 * tm + 1];
#pragma unroll
        for (int q = 0; q < 4; ++q) {
          const float w = Ws[kk][q * 4 + tj];
          acc[q][0] = fmaf(x0, w, acc[q][0]);
          acc[q][1] = fmaf(x1, w, acc[q][1]);
        }
      }
      __syncthreads();
    }
  }
  // combine the two K halves
  if (kg == 1) {
#pragma unroll
    for (int q = 0; q < 4; ++q) {
      Red[tid - 64][q * 2 + 0] = acc[q][0];
      Red[tid - 64][q * 2 + 1] = acc[q][1];
    }
  }
  __syncthreads();
  if (kg == 0) {
#pragma unroll
    for (int q = 0; q < 4; ++q) {
      acc[q][0] += Red[tid][q * 2 + 0];
      acc[q][1] += Red[tid][q * 2 + 1];
    }
    const int j = j0 + tj;
#pragma unroll
    for (int mm = 0; mm < 2; ++mm) {
      const int m = 2 * tm + mm;
      float gi = acc[0][mm], gf = acc[1][mm], gg = acc[2][mm], go = acc[3][mm];
      if (IS_L1) {
        gi += bih[0 * kH + j] + bhh[0 * kH + j];
        gf += bih[1 * kH + j] + bhh[1 * kH + j];
        gg += bih[2 * kH + j] + bhh[2 * kH + j];
        go += bih[3 * kH + j] + bhh[3 * kH + j];
      } else {
        gi += xproj[m * kG + 0 * kH + j];
        gf += xproj[m * kG + 1 * kH + j];
        gg += xproj[m * kG + 2 * kH + j];
        go += xproj[m * kG + 3 * kH + j];
      }
      const float cold = c_io[m * kH + j];
      const float cnew = sigmoid_f(gf) * cold + sigmoid_f(gi) * tanhf(gg);
      const float hnew = sigmoid_f(go) * tanhf(cnew);
      c_io[m * kH + j] = cnew;
      h_out[m * kH + j] = hnew;
      if (h_top) h_top[m * kH + j] = hnew;
    }
  }
}

}  // namespace

extern "C" void kernel_launch(void* const* d_in, const int* in_sizes, int n_in,
                              void* d_out, int out_size, void* d_ws, size_t ws_size,
                              hipStream_t stream) {
  const int* input_ids = (const int*)d_in[0];
  const int* output_ids = (const int*)d_in[1];
  const float* enc_emb = (const float*)d_in[2];
  const float* enc_Wih = (const float*)d_in[3];
  const float* enc_Whh = (const float*)d_in[4];
  const float* enc_bih = (const float*)d_in[5];
  const float* enc_bhh = (const float*)d_in[6];
  const float* dec_emb = (const float*)d_in[7];
  const float* dec_Wih = (const float*)d_in[8];
  const float* dec_Whh = (const float*)d_in[9];
  const float* dec_bih = (const float*)d_in[10];
  const float* dec_bhh = (const float*)d_in[11];
  const float* Wout = (const float*)d_in[12];
  const float* bout = (const float*)d_in[13];
  float* out = (float*)d_out;
  float* ws = (float*)d_ws;

  // workspace layout (floats): ~18.9M floats = ~76 MB
  float* xproj_enc = ws;                                      // T*B*G
  float* xproj_dec = xproj_enc + (size_t)kT * kB * kG;        // (T-1)*B*G
  float* hA = xproj_dec + (size_t)(kT - 1) * kB * kG;         // L*B*H
  float* hB = hA + (size_t)2 * kB * kH;                       // L*B*H
  float* cbuf = hB + (size_t)2 * kB * kH;                     // L*B*H
  float* htop = cbuf + (size_t)2 * kB * kH;                   // (T-1)*B*H

  const size_t LBH = (size_t)kB * kH;  // per-layer h/c stride

  // zero h (both buffers) and c — contiguous region of 3 * L * B * H floats
  hipMemsetAsync(hA, 0, sizeof(float) * 3 * 2 * kB * kH, stream);

  // layer-0 input projections for all timesteps (bias pre-added)
  proj_gather_gemm<<<dim3(16, 32), 256, 0, stream>>>(
      enc_emb, input_ids, enc_Wih, enc_bih, enc_bhh, xproj_enc, kT * kB);
  proj_gather_gemm<<<dim3(16, 32), 256, 0, stream>>>(
      dec_emb, output_ids, dec_Wih, dec_bih, dec_bhh, xproj_dec, (kT - 1) * kB);

  const size_t WL = (size_t)kG * kH;  // per-layer weight stride

  float* hin = hA;
  float* hout = hB;
  for (int t = 0; t < kT; ++t) {
    lstm_cell<false><<<256, 128, 0, stream>>>(
        hin, nullptr, xproj_enc + (size_t)t * kB * kG, nullptr, enc_Whh,
        nullptr, nullptr, cbuf, hout, nullptr);
    lstm_cell<true><<<256, 128, 0, stream>>>(
        hin + LBH, hout, nullptr, enc_Wih + WL, enc_Whh + WL,
        enc_bih + kG, enc_bhh + kG, cbuf + LBH, hout + LBH, nullptr);
    float* tmp = hin; hin = hout; hout = tmp;
  }
  for (int s = 0; s < kT - 1; ++s) {
    lstm_cell<false><<<256, 128, 0, stream>>>(
        hin, nullptr, xproj_dec + (size_t)s * kB * kG, nullptr, dec_Whh,
        nullptr, nullptr, cbuf, hout, nullptr);
    lstm_cell<true><<<256, 128, 0, stream>>>(
        hin + LBH, hout, nullptr, dec_Wih + WL, dec_Whh + WL,
        dec_bih + kG, dec_bhh + kG, cbuf + LBH, hout + LBH,
        htop + (size_t)s * kB * kH);
    float* tmp = hin; hin = hout; hout = tmp;
  }

  // logits[:, 0, :]
  zero_t0_kernel<<<(kB * kV + 255) / 256, 256, 0, stream>>>(out);
  ones_t0_kernel<<<1, kB * kB, 0, stream>>>(output_ids, out);

  // logits[:, 1:, :] — batched over all 63 decoder steps
  out_gemm<<<dim3(16, kV / 128), 256, 0, stream>>>(htop, Wout, bout, out);
}

// Round 2
// 2481.170 us; speedup vs baseline: 4.0944x; 4.0944x over previous
//
#include <hip/hip_runtime.h>

namespace {

constexpr int kB = 32;
constexpr int kT = 64;
constexpr int kH = 1024;
constexpr int kE = 1024;
constexpr int kV = 16000;
constexpr int kG = 4096;  // 4*H

typedef __attribute__((ext_vector_type(8))) short short8v;
typedef __attribute__((ext_vector_type(4))) float f32x4;

__device__ __forceinline__ float sigmoid_f(float x) {
  return 1.0f / (1.0f + __expf(-x));
}
__device__ __forceinline__ unsigned short f2bf(float x) {
  unsigned int u = __builtin_bit_cast(unsigned int, x);
  u = (u + 0x7FFFu + ((u >> 16) & 1u)) >> 16;
  return (unsigned short)u;
}
__device__ __forceinline__ float bf2f(unsigned short h) {
  return __builtin_bit_cast(float, (unsigned int)h << 16);
}

// ---------------- t=0 logits slice ----------------
__global__ void zero_t0_kernel(float* __restrict__ out) {
  int idx = blockIdx.x * blockDim.x + threadIdx.x;
  if (idx >= kB * kV) return;
  int b = idx / kV, v = idx % kV;
  out[(size_t)b * kT * kV + v] = 0.0f;
}

// JAX outer-index semantics: out[b, 0, output_ids[j, 0]] = 1 for ALL (b, j)
__global__ void ones_t0_kernel(const int* __restrict__ output_ids,
                               float* __restrict__ out) {
  int b = threadIdx.x >> 5;
  int j = threadIdx.x & 31;
  int id = output_ids[j * kT];
  out[(size_t)b * kT * kV + id] = 1.0f;
}

// ---- weight convert: fp32 row-major (4096,1024) -> bf16 MFMA B-frag order.
// chunk idx -> lane=idx&63, s=(idx>>6)&31, rg=idx>>11;
// value[e] = W[rg*16 + (lane&15)][s*32 + (lane>>4)*8 + e]
struct W6 {
  const float* src[6];
  unsigned short* dst[6];
};
__global__ __launch_bounds__(256)
void convert_w6(W6 S) {
  const int mat = blockIdx.x >> 11;
  const int idx = (blockIdx.x & 2047) * 256 + threadIdx.x;  // 0..524287
  const float* __restrict__ src = S.src[mat];
  unsigned short* __restrict__ dst = S.dst[mat];
  const int lane = idx & 63;
  const int s = (idx >> 6) & 31;
  const int rg = idx >> 11;
  const int row = rg * 16 + (lane & 15);
  const int k = s * 32 + ((lane >> 4) << 3);
  const float4* p = reinterpret_cast<const float4*>(src + (size_t)row * kH + k);
  float4 v0 = p[0], v1 = p[1];
  short8v o;
  o[0] = (short)f2bf(v0.x); o[1] = (short)f2bf(v0.y);
  o[2] = (short)f2bf(v0.z); o[3] = (short)f2bf(v0.w);
  o[4] = (short)f2bf(v1.x); o[5] = (short)f2bf(v1.y);
  o[6] = (short)f2bf(v1.z); o[7] = (short)f2bf(v1.w);
  *reinterpret_cast<short8v*>(dst + (size_t)idx * 8) = o;
}

// ---- proj: C_bf16[m, n] = emb[id(m), :] . W[n, :] + b0[n] + b1[n]
__global__ __launch_bounds__(256)
void proj_gather_gemm(const float* __restrict__ emb, const int* __restrict__ ids,
                      const float* __restrict__ W, const float* __restrict__ b0,
                      const float* __restrict__ b1, unsigned short* __restrict__ C,
                      int M) {
  __shared__ alignas(16) float As[16][132];
  __shared__ alignas(16) float Ws[16][132];
  const int bm = blockIdx.x * 128;
  const int bn = blockIdx.y * 128;
  const int tid = threadIdx.x;
  const int tx = tid & 15;
  const int ty = tid >> 4;
  float acc[8][8] = {};
  for (int k0 = 0; k0 < kH; k0 += 16) {
#pragma unroll
    for (int p = 0; p < 2; ++p) {
      const int ff = tid + p * 256;
      const int r = ff >> 2;
      const int kc = ff & 3;
      const int m = bm + r;
      float4 av = make_float4(0.f, 0.f, 0.f, 0.f);
      if (m < M) {
        const int tt = m >> 5, bb = m & 31;
        const int id = ids[bb * kT + tt];
        av = *reinterpret_cast<const float4*>(&emb[(size_t)id * kE + k0 + kc * 4]);
      }
      As[kc * 4 + 0][r] = av.x; As[kc * 4 + 1][r] = av.y;
      As[kc * 4 + 2][r] = av.z; As[kc * 4 + 3][r] = av.w;
      const float4 wv =
          *reinterpret_cast<const float4*>(&W[(size_t)(bn + r) * kH + k0 + kc * 4]);
      Ws[kc * 4 + 0][r] = wv.x; Ws[kc * 4 + 1][r] = wv.y;
      Ws[kc * 4 + 2][r] = wv.z; Ws[kc * 4 + 3][r] = wv.w;
    }
    __syncthreads();
#pragma unroll
    for (int kk = 0; kk < 16; ++kk) {
      float a[8], w[8];
      *reinterpret_cast<float4*>(&a[0]) = *reinterpret_cast<const float4*>(&As[kk][ty * 4]);
      *reinterpret_cast<float4*>(&a[4]) = *reinterpret_cast<const float4*>(&As[kk][64 + ty * 4]);
      *reinterpret_cast<float4*>(&w[0]) = *reinterpret_cast<const float4*>(&Ws[kk][tx * 4]);
      *reinterpret_cast<float4*>(&w[4]) = *reinterpret_cast<const float4*>(&Ws[kk][64 + tx * 4]);
#pragma unroll
      for (int i = 0; i < 8; ++i)
#pragma unroll
        for (int j = 0; j < 8; ++j) acc[i][j] = fmaf(a[i], w[j], acc[i][j]);
    }
    __syncthreads();
  }
#pragma unroll
  for (int i = 0; i < 8; ++i) {
    const int m = bm + ty * 4 + (i >> 2) * 64 + (i & 3);
    if (m >= M) continue;
#pragma unroll
    for (int j = 0; j < 8; ++j) {
      const int n = bn + tx * 4 + (j >> 2) * 64 + (j & 3);
      C[(size_t)m * kG + n] = f2bf(acc[i][j] + b0[n] + b1[n]);
    }
  }
}

// ---- output GEMM (fp32): logits[b, s+1, v] = htop[s*B+b, :] . Wout[v, :] + bout[v]
__global__ __launch_bounds__(256)
void out_gemm(const float* __restrict__ A, const float* __restrict__ W,
              const float* __restrict__ bias, float* __restrict__ out) {
  constexpr int M = (kT - 1) * kB;  // 2016
  __shared__ alignas(16) float As[16][132];
  __shared__ alignas(16) float Ws[16][132];
  const int bm = blockIdx.x * 128;
  const int bn = blockIdx.y * 128;
  const int tid = threadIdx.x;
  const int tx = tid & 15;
  const int ty = tid >> 4;
  float acc[8][8] = {};
  for (int k0 = 0; k0 < kH; k0 += 16) {
#pragma unroll
    for (int p = 0; p < 2; ++p) {
      const int ff = tid + p * 256;
      const int r = ff >> 2;
      const int kc = ff & 3;
      const int m = bm + r;
      float4 av = make_float4(0.f, 0.f, 0.f, 0.f);
      if (m < M) av = *reinterpret_cast<const float4*>(&A[(size_t)m * kH + k0 + kc * 4]);
      As[kc * 4 + 0][r] = av.x; As[kc * 4 + 1][r] = av.y;
      As[kc * 4 + 2][r] = av.z; As[kc * 4 + 3][r] = av.w;
      const float4 wv =
          *reinterpret_cast<const float4*>(&W[(size_t)(bn + r) * kH + k0 + kc * 4]);
      Ws[kc * 4 + 0][r] = wv.x; Ws[kc * 4 + 1][r] = wv.y;
      Ws[kc * 4 + 2][r] = wv.z; Ws[kc * 4 + 3][r] = wv.w;
    }
    __syncthreads();
#pragma unroll
    for (int kk = 0; kk < 16; ++kk) {
      float a[8], w[8];
      *reinterpret_cast<float4*>(&a[0]) = *reinterpret_cast<const float4*>(&As[kk][ty * 4]);
      *reinterpret_cast<float4*>(&a[4]) = *reinterpret_cast<const float4*>(&As[kk][64 + ty * 4]);
      *reinterpret_cast<float4*>(&w[0]) = *reinterpret_cast<const float4*>(&Ws[kk][tx * 4]);
      *reinterpret_cast<float4*>(&w[4]) = *reinterpret_cast<const float4*>(&Ws[kk][64 + tx * 4]);
#pragma unroll
      for (int i = 0; i < 8; ++i)
#pragma unroll
        for (int j = 0; j < 8; ++j) acc[i][j] = fmaf(a[i], w[j], acc[i][j]);
    }
    __syncthreads();
  }
#pragma unroll
  for (int i = 0; i < 8; ++i) {
    const int m = bm + ty * 4 + (i >> 2) * 64 + (i & 3);
    if (m >= M) continue;
    const int s = m >> 5, bb = m & 31;
    float* orow = out + (size_t)bb * kT * kV + (size_t)(s + 1) * kV;
#pragma unroll
    for (int j = 0; j < 8; ++j) {
      const int n = bn + tx * 4 + (j >> 2) * 64 + (j & 3);
      orow[n] = acc[i][j] + bias[n];
    }
  }
}

// ---- fused MFMA LSTM cell(s). One kernel runs up to 2 independent jobs
// (layer1 of step t, layer0 of step t+1). 64 blocks per job, 16 waves/block.
// Wave (g=wave>>2, kq=wave&3) computes gate g, K-quarter kq, for 16 hidden
// units (ug = blockIdx&63) over all 32 batch rows via 2x mfma 16x16x32 bf16.
struct Job {
  const unsigned short* A0;     // phase-0 A frags (x input) or null
  const unsigned short* W0;     // phase-0 W frags
  const unsigned short* A1;     // phase-1 A frags (h input)
  const unsigned short* W1;     // phase-1 W frags
  const unsigned short* xproj;  // bf16 [32][4096] addend (L0) or null
  const float* bih;             // L1 addend (layer-1 slice base)
  const float* bhh;
  float* c;                     // fp32 [32][1024]
  unsigned short* h_swz;        // bf16 A-frag layout out
  float* h_top;                 // fp32 [32][1024] out or null
};
struct CellPair { Job j[2]; };

__global__ __launch_bounds__(1024)
void lstm_cells(CellPair P) {
  const Job J = (blockIdx.x >= 64) ? P.j[1] : P.j[0];
  const int ug = blockIdx.x & 63;
  const int wave = threadIdx.x >> 6;
  const int lane = threadIdx.x & 63;
  const int g = wave >> 2, kq = wave & 3;

  f32x4 acc0 = {0.f, 0.f, 0.f, 0.f};
  f32x4 acc1 = {0.f, 0.f, 0.f, 0.f};
  const size_t wrow = (size_t)(g * 64 + ug) * 32 * 512;  // elems

#pragma unroll 1
  for (int ph = 0; ph < 2; ++ph) {
    const unsigned short* Ap = ph ? J.A1 : J.A0;
    const unsigned short* Wp = ph ? J.W1 : J.W0;
    if (!Ap) continue;
#pragma unroll
    for (int s = 0; s < 8; ++s) {
      const int gs = kq * 8 + s;
      short8v a0 = *reinterpret_cast<const short8v*>(Ap + (size_t)(gs * 64 + lane) * 8);
      short8v a1 = *reinterpret_cast<const short8v*>(Ap + (size_t)((32 + gs) * 64 + lane) * 8);
      short8v bv = *reinterpret_cast<const short8v*>(Wp + wrow + (size_t)(gs * 64 + lane) * 8);
      acc0 = __builtin_amdgcn_mfma_f32_16x16x32_bf16(a0, bv, acc0, 0, 0, 0);
      acc1 = __builtin_amdgcn_mfma_f32_16x16x32_bf16(a1, bv, acc1, 0, 0, 0);
    }
  }

  __shared__ alignas(16) float Ls[16][2][64][4];
  *reinterpret_cast<f32x4*>(&Ls[wave][0][lane][0]) = acc0;
  *reinterpret_cast<f32x4*>(&Ls[wave][1][lane][0]) = acc1;
  __syncthreads();

  if (threadIdx.x < 512) {
    const int m = threadIdx.x >> 4;   // 0..31
    const int ul = threadIdx.x & 15;  // 0..15
    const int u = ug * 16 + ul;
    const int mt = m >> 4;
    const int r = m & 3;
    const int lane2 = ul | ((m & 12) << 2);
    float gate[4];
#pragma unroll
    for (int q = 0; q < 4; ++q) {
      float v = Ls[q * 4 + 0][mt][lane2][r] + Ls[q * 4 + 1][mt][lane2][r] +
                Ls[q * 4 + 2][mt][lane2][r] + Ls[q * 4 + 3][mt][lane2][r];
      if (J.xproj) {
        v += bf2f(J.xproj[m * kG + q * kH + u]);
      } else {
        v += J.bih[q * kH + u] + J.bhh[q * kH + u];
      }
      gate[q] = v;
    }
    const float cold = J.c[m * kH + u];
    const float iv = sigmoid_f(gate[0]);
    const float fv = sigmoid_f(gate[1]);
    const float gv = tanhf(gate[2]);
    const float ov = sigmoid_f(gate[3]);
    const float cnew = fv * cold + iv * gv;
    const float hnew = ov * tanhf(cnew);
    J.c[m * kH + u] = cnew;
    // h in A-frag layout: h[mt*16+(lane&15)][ks*32+(lane>>4)*8+e]
    const int ks = u >> 5;
    const int lane3 = (m & 15) | (((u >> 3) & 3) << 4);
    const int e = u & 7;
    J.h_swz[(size_t)((mt * 32 + ks) * 64 + lane3) * 8 + e] = f2bf(hnew);
    if (J.h_top) J.h_top[m * kH + u] = hnew;
  }
}

}  // namespace

extern "C" void kernel_launch(void* const* d_in, const int* in_sizes, int n_in,
                              void* d_out, int out_size, void* d_ws, size_t ws_size,
                              hipStream_t stream) {
  const int* input_ids = (const int*)d_in[0];
  const int* output_ids = (const int*)d_in[1];
  const float* enc_emb = (const float*)d_in[2];
  const float* enc_Wih = (const float*)d_in[3];
  const float* enc_Whh = (const float*)d_in[4];
  const float* enc_bih = (const float*)d_in[5];
  const float* enc_bhh = (const float*)d_in[6];
  const float* dec_emb = (const float*)d_in[7];
  const float* dec_Wih = (const float*)d_in[8];
  const float* dec_Whh = (const float*)d_in[9];
  const float* dec_bih = (const float*)d_in[10];
  const float* dec_bhh = (const float*)d_in[11];
  const float* Wout = (const float*)d_in[12];
  const float* bout = (const float*)d_in[13];
  float* out = (float*)d_out;
  char* ws = (char*)d_ws;

  const size_t WL = (size_t)kG * kH;  // per-layer weight stride (elems)

  // ---- workspace layout (bytes) ----
  size_t off = 0;
  unsigned short* xproj_enc = (unsigned short*)(ws + off); off += (size_t)kT * kB * kG * 2;
  unsigned short* xproj_dec = (unsigned short*)(ws + off); off += (size_t)(kT - 1) * kB * kG * 2;
  float* htop = (float*)(ws + off); off += (size_t)(kT - 1) * kB * kH * 4;
  float* c0 = (float*)(ws + off); off += (size_t)kB * kH * 4;
  float* c1 = (float*)(ws + off); off += (size_t)kB * kH * 4;
  unsigned short* h0swz[2];
  unsigned short* h1swz[2];
  h0swz[0] = (unsigned short*)(ws + off); off += (size_t)kB * kH * 2;
  h0swz[1] = (unsigned short*)(ws + off); off += (size_t)kB * kH * 2;
  h1swz[0] = (unsigned short*)(ws + off); off += (size_t)kB * kH * 2;
  h1swz[1] = (unsigned short*)(ws + off); off += (size_t)kB * kH * 2;
  unsigned short* wswz[6];
  for (int i = 0; i < 6; ++i) { wswz[i] = (unsigned short*)(ws + off); off += WL * 2; }

  // zero c0,c1,h0swz[0..1],h1swz[0..1] (contiguous)
  hipMemsetAsync(c0, 0, (size_t)kB * kH * (4 + 4 + 2 + 2 + 2 + 2), stream);

  // one-time bf16 fragment-swizzled weight conversion
  W6 S;
  S.src[0] = enc_Whh;       S.dst[0] = wswz[0];  // enc Whh l0
  S.src[1] = enc_Wih + WL;  S.dst[1] = wswz[1];  // enc Wih l1
  S.src[2] = enc_Whh + WL;  S.dst[2] = wswz[2];  // enc Whh l1
  S.src[3] = dec_Whh;       S.dst[3] = wswz[3];  // dec Whh l0
  S.src[4] = dec_Wih + WL;  S.dst[4] = wswz[4];  // dec Wih l1
  S.src[5] = dec_Whh + WL;  S.dst[5] = wswz[5];  // dec Whh l1
  convert_w6<<<6 * 2048, 256, 0, stream>>>(S);

  // layer-0 input projections for all timesteps (bias pre-added, bf16 out)
  proj_gather_gemm<<<dim3(16, 32), 256, 0, stream>>>(
      enc_emb, input_ids, enc_Wih, enc_bih, enc_bhh, xproj_enc, kT * kB);
  proj_gather_gemm<<<dim3(16, 32), 256, 0, stream>>>(
      dec_emb, output_ids, dec_Wih, dec_bih, dec_bhh, xproj_dec, (kT - 1) * kB);

  // ---- recurrence: kernels p=0..127; K_p = {L1(p-1), L0(p)} where valid.
  // total conceptual steps t = 0..126 (64 enc + 63 dec).
  auto makeL0 = [&](int t) {
    Job j = {};
    j.A1 = h0swz[t & 1];
    j.W1 = (t < kT) ? wswz[0] : wswz[3];
    j.xproj = (t < kT) ? (xproj_enc + (size_t)t * kB * kG)
                       : (xproj_dec + (size_t)(t - kT) * kB * kG);
    j.c = c0;
    j.h_swz = h0swz[(t + 1) & 1];
    return j;
  };
  auto makeL1 = [&](int t) {
    Job j = {};
    j.A0 = h0swz[(t + 1) & 1];  // h0_t, written by L0(t) in previous kernel
    j.W0 = (t < kT) ? wswz[1] : wswz[4];
    j.A1 = h1swz[t & 1];
    j.W1 = (t < kT) ? wswz[2] : wswz[5];
    j.bih = ((t < kT) ? enc_bih : dec_bih) + kG;
    j.bhh = ((t < kT) ? enc_bhh : dec_bhh) + kG;
    j.c = c1;
    j.h_swz = h1swz[(t + 1) & 1];
    j.h_top = (t >= kT) ? (htop + (size_t)(t - kT) * kB * kH) : nullptr;
    return j;
  };

  constexpr int kSteps = kT + (kT - 1);  // 127
  {
    CellPair P; P.j[0] = makeL0(0); P.j[1] = P.j[0];
    lstm_cells<<<64, 1024, 0, stream>>>(P);
  }
  for (int p = 1; p <= kSteps - 1; ++p) {
    CellPair P;
    P.j[0] = makeL1(p - 1);
    P.j[1] = makeL0(p);
    lstm_cells<<<128, 1024, 0, stream>>>(P);
  }
  {
    CellPair P; P.j[0] = makeL1(kSteps - 1); P.j[1] = P.j[0];
    lstm_cells<<<64, 1024, 0, stream>>>(P);
  }

  // logits[:, 0, :]
  zero_t0_kernel<<<(kB * kV + 255) / 256, 256, 0, stream>>>(out);
  ones_t0_kernel<<<1, kB * kB, 0, stream>>>(output_ids, out);

  // logits[:, 1:, :]
  out_gemm<<<dim3(16, kV / 128), 256, 0, stream>>>(htop, Wout, bout, out);
}

// Round 3
// 1471.297 us; speedup vs baseline: 6.9048x; 1.6864x over previous
//
#include <hip/hip_runtime.h>

namespace {

constexpr int kB = 32;
constexpr int kT = 64;
constexpr int kH = 1024;
constexpr int kE = 1024;
constexpr int kV = 16000;
constexpr int kG = 4096;  // 4*H

typedef __attribute__((ext_vector_type(8))) short short8v;
typedef __attribute__((ext_vector_type(4))) float f32x4;

__device__ __forceinline__ float sigmoid_f(float x) {
  return 1.0f / (1.0f + __expf(-x));
}
__device__ __forceinline__ unsigned short f2bf(float x) {
  unsigned int u = __builtin_bit_cast(unsigned int, x);
  u = (u + 0x7FFFu + ((u >> 16) & 1u)) >> 16;
  return (unsigned short)u;
}
__device__ __forceinline__ float bf2f(unsigned short h) {
  return __builtin_bit_cast(float, (unsigned int)h << 16);
}

// ---------------- t=0 logits slice ----------------
__global__ void zero_t0_kernel(float* __restrict__ out) {
  int idx = blockIdx.x * blockDim.x + threadIdx.x;
  if (idx >= kB * kV) return;
  int b = idx / kV, v = idx % kV;
  out[(size_t)b * kT * kV + v] = 0.0f;
}

// JAX outer-index semantics: out[b, 0, output_ids[j, 0]] = 1 for ALL (b, j)
__global__ void ones_t0_kernel(const int* __restrict__ output_ids,
                               float* __restrict__ out) {
  int b = threadIdx.x >> 5;
  int j = threadIdx.x & 31;
  int id = output_ids[j * kT];
  out[(size_t)b * kT * kV + id] = 1.0f;
}

// ---- generic weight convert: fp32 row-major (R,1024) -> bf16 MFMA frag order.
// chunk idx -> lane=idx&63, s=(idx>>6)&31, rg=idx>>11;
// value[e] = W[rg*16 + (lane&15)][s*32 + (lane>>4)*8 + e]
__global__ __launch_bounds__(256)
void convert_frag(const float* __restrict__ src, unsigned short* __restrict__ dst,
                  int nchunks) {
  const int idx = blockIdx.x * 256 + threadIdx.x;
  if (idx >= nchunks) return;
  const int lane = idx & 63;
  const int s = (idx >> 6) & 31;
  const int rg = idx >> 11;
  const int row = rg * 16 + (lane & 15);
  const int k = s * 32 + ((lane >> 4) << 3);
  const float4* p = reinterpret_cast<const float4*>(src + (size_t)row * kH + k);
  float4 v0 = p[0], v1 = p[1];
  short8v o;
  o[0] = (short)f2bf(v0.x); o[1] = (short)f2bf(v0.y);
  o[2] = (short)f2bf(v0.z); o[3] = (short)f2bf(v0.w);
  o[4] = (short)f2bf(v1.x); o[5] = (short)f2bf(v1.y);
  o[6] = (short)f2bf(v1.z); o[7] = (short)f2bf(v1.w);
  *reinterpret_cast<short8v*>(dst + (size_t)idx * 8) = o;
}

// ---- gather embedding rows into A-frag bf16 layout.
// m = tile*16 + (lane&15); t = m>>5; b = m&31; id = ids[b*kT + t]
__global__ __launch_bounds__(256)
void gather_frag(const float* __restrict__ emb, const int* __restrict__ ids,
                 unsigned short* __restrict__ dst, int ntiles) {
  const int idx = blockIdx.x * 256 + threadIdx.x;
  const int lane = idx & 63;
  const int s = (idx >> 6) & 31;
  const int tile = idx >> 11;
  if (tile >= ntiles) return;
  const int m = tile * 16 + (lane & 15);
  const int t = m >> 5, b = m & 31;
  const int id = ids[b * kT + t];
  const int k = s * 32 + ((lane >> 4) << 3);
  const float4* p = reinterpret_cast<const float4*>(emb + (size_t)id * kE + k);
  float4 v0 = p[0], v1 = p[1];
  short8v o;
  o[0] = (short)f2bf(v0.x); o[1] = (short)f2bf(v0.y);
  o[2] = (short)f2bf(v0.z); o[3] = (short)f2bf(v0.w);
  o[4] = (short)f2bf(v1.x); o[5] = (short)f2bf(v1.y);
  o[6] = (short)f2bf(v1.z); o[7] = (short)f2bf(v1.w);
  *reinterpret_cast<short8v*>(dst + (size_t)idx * 8) = o;
}

// ---- proj MFMA: xproj_bf16[m][4096] = xin . W^T + b0 + b1
// Block 256 thr = 4 waves; tile 64 rows x 128 cols; wave w: 4 m-tiles, 2 n-tiles.
__global__ __launch_bounds__(256)
void proj_mfma(const unsigned short* __restrict__ Af,
               const unsigned short* __restrict__ Bf,
               const float* __restrict__ b0, const float* __restrict__ b1,
               unsigned short* __restrict__ dst, int nmt) {
  const int w = threadIdx.x >> 6, lane = threadIdx.x & 63;
  const int mg = blockIdx.x, ng = blockIdx.y;
  f32x4 acc[4][2] = {};
  const unsigned short* Ab[4];
  const unsigned short* Bb[2];
#pragma unroll
  for (int i = 0; i < 4; ++i) {
    int tile = mg * 4 + i;
    if (tile > nmt - 1) tile = nmt - 1;
    Ab[i] = Af + (size_t)tile * 16384 + lane * 8;
  }
#pragma unroll
  for (int j = 0; j < 2; ++j) {
    const int nt = ng * 8 + w * 2 + j;
    Bb[j] = Bf + (size_t)nt * 16384 + lane * 8;
  }
#pragma unroll 2
  for (int s = 0; s < 32; ++s) {
    short8v a[4], b[2];
#pragma unroll
    for (int i = 0; i < 4; ++i) a[i] = *reinterpret_cast<const short8v*>(Ab[i] + s * 512);
#pragma unroll
    for (int j = 0; j < 2; ++j) b[j] = *reinterpret_cast<const short8v*>(Bb[j] + s * 512);
#pragma unroll
    for (int i = 0; i < 4; ++i)
#pragma unroll
      for (int j = 0; j < 2; ++j)
        acc[i][j] = __builtin_amdgcn_mfma_f32_16x16x32_bf16(a[i], b[j], acc[i][j], 0, 0, 0);
  }
#pragma unroll
  for (int i = 0; i < 4; ++i) {
    const int tile = mg * 4 + i;
    if (tile >= nmt) continue;
    const int mbase = tile * 16 + ((lane >> 4) << 2);
#pragma unroll
    for (int j = 0; j < 2; ++j) {
      const int n = (ng * 8 + w * 2 + j) * 16 + (lane & 15);
      const float bj = b0[n] + b1[n];
#pragma unroll
      for (int r = 0; r < 4; ++r) {
        dst[(size_t)(mbase + r) * kG + n] = f2bf(acc[i][j][r] + bj);
      }
    }
  }
}

// ---- output GEMM MFMA: logits[b, s+1, v] from htop frags (126 m-tiles) x Wout frags
__global__ __launch_bounds__(256)
void out_gemm_mfma(const unsigned short* __restrict__ Af,
                   const unsigned short* __restrict__ Bf,
                   const float* __restrict__ bias, float* __restrict__ out) {
  const int w = threadIdx.x >> 6, lane = threadIdx.x & 63;
  const int mg = blockIdx.x, ng = blockIdx.y;
  f32x4 acc[4][2] = {};
  const unsigned short* Ab[4];
  const unsigned short* Bb[2];
#pragma unroll
  for (int i = 0; i < 4; ++i) {
    int tile = mg * 4 + i;
    if (tile > 125) tile = 125;
    Ab[i] = Af + (size_t)tile * 16384 + lane * 8;
  }
#pragma unroll
  for (int j = 0; j < 2; ++j) {
    const int nt = ng * 8 + w * 2 + j;
    Bb[j] = Bf + (size_t)nt * 16384 + lane * 8;
  }
#pragma unroll 2
  for (int s = 0; s < 32; ++s) {
    short8v a[4], b[2];
#pragma unroll
    for (int i = 0; i < 4; ++i) a[i] = *reinterpret_cast<const short8v*>(Ab[i] + s * 512);
#pragma unroll
    for (int j = 0; j < 2; ++j) b[j] = *reinterpret_cast<const short8v*>(Bb[j] + s * 512);
#pragma unroll
    for (int i = 0; i < 4; ++i)
#pragma unroll
      for (int j = 0; j < 2; ++j)
        acc[i][j] = __builtin_amdgcn_mfma_f32_16x16x32_bf16(a[i], b[j], acc[i][j], 0, 0, 0);
  }
#pragma unroll
  for (int i = 0; i < 4; ++i) {
    const int tile = mg * 4 + i;
    if (tile >= 126) continue;
    const int mbase = tile * 16 + ((lane >> 4) << 2);
#pragma unroll
    for (int j = 0; j < 2; ++j) {
      const int n = (ng * 8 + w * 2 + j) * 16 + (lane & 15);
      const float bj = bias[n];
#pragma unroll
      for (int r = 0; r < 4; ++r) {
        const int m = mbase + r;
        const int sd = m >> 5, bb = m & 31;
        out[(size_t)bb * kT * kV + (size_t)(sd + 1) * kV + n] = acc[i][j][r] + bj;
      }
    }
  }
}

// ---- fused MFMA LSTM cell(s): unchanged structure; h_top now bf16 A-frag out.
struct Job {
  const unsigned short* A0;
  const unsigned short* W0;
  const unsigned short* A1;
  const unsigned short* W1;
  const unsigned short* xproj;  // bf16 [32][4096] addend (L0) or null
  const float* bih;
  const float* bhh;
  float* c;
  unsigned short* h_swz;
  unsigned short* h_top;  // bf16 A-frag copy or null
};
struct CellPair { Job j[2]; };

__global__ __launch_bounds__(1024)
void lstm_cells(CellPair P) {
  const Job J = (blockIdx.x >= 64) ? P.j[1] : P.j[0];
  const int ug = blockIdx.x & 63;
  const int wave = threadIdx.x >> 6;
  const int lane = threadIdx.x & 63;
  const int g = wave >> 2, kq = wave & 3;

  f32x4 acc0 = {0.f, 0.f, 0.f, 0.f};
  f32x4 acc1 = {0.f, 0.f, 0.f, 0.f};
  const size_t wrow = (size_t)(g * 64 + ug) * 32 * 512;  // elems

#pragma unroll 1
  for (int ph = 0; ph < 2; ++ph) {
    const unsigned short* Ap = ph ? J.A1 : J.A0;
    const unsigned short* Wp = ph ? J.W1 : J.W0;
    if (!Ap) continue;
#pragma unroll
    for (int s = 0; s < 8; ++s) {
      const int gs = kq * 8 + s;
      short8v a0 = *reinterpret_cast<const short8v*>(Ap + (size_t)(gs * 64 + lane) * 8);
      short8v a1 = *reinterpret_cast<const short8v*>(Ap + (size_t)((32 + gs) * 64 + lane) * 8);
      short8v bv = *reinterpret_cast<const short8v*>(Wp + wrow + (size_t)(gs * 64 + lane) * 8);
      acc0 = __builtin_amdgcn_mfma_f32_16x16x32_bf16(a0, bv, acc0, 0, 0, 0);
      acc1 = __builtin_amdgcn_mfma_f32_16x16x32_bf16(a1, bv, acc1, 0, 0, 0);
    }
  }

  __shared__ alignas(16) float Ls[16][2][64][4];
  *reinterpret_cast<f32x4*>(&Ls[wave][0][lane][0]) = acc0;
  *reinterpret_cast<f32x4*>(&Ls[wave][1][lane][0]) = acc1;
  __syncthreads();

  if (threadIdx.x < 512) {
    const int m = threadIdx.x >> 4;   // 0..31
    const int ul = threadIdx.x & 15;  // 0..15
    const int u = ug * 16 + ul;
    const int mt = m >> 4;
    const int r = m & 3;
    const int lane2 = ul | ((m & 12) << 2);
    float gate[4];
#pragma unroll
    for (int q = 0; q < 4; ++q) {
      float v = Ls[q * 4 + 0][mt][lane2][r] + Ls[q * 4 + 1][mt][lane2][r] +
                Ls[q * 4 + 2][mt][lane2][r] + Ls[q * 4 + 3][mt][lane2][r];
      if (J.xproj) {
        v += bf2f(J.xproj[m * kG + q * kH + u]);
      } else {
        v += J.bih[q * kH + u] + J.bhh[q * kH + u];
      }
      gate[q] = v;
    }
    const float cold = J.c[m * kH + u];
    const float iv = sigmoid_f(gate[0]);
    const float fv = sigmoid_f(gate[1]);
    const float gv = tanhf(gate[2]);
    const float ov = sigmoid_f(gate[3]);
    const float cnew = fv * cold + iv * gv;
    const float hnew = ov * tanhf(cnew);
    J.c[m * kH + u] = cnew;
    const int ks = u >> 5;
    const int lane3 = (m & 15) | (((u >> 3) & 3) << 4);
    const int e = u & 7;
    const size_t fidx = (size_t)((mt * 32 + ks) * 64 + lane3) * 8 + e;
    const unsigned short hb = f2bf(hnew);
    J.h_swz[fidx] = hb;
    if (J.h_top) J.h_top[fidx] = hb;
  }
}

}  // namespace

extern "C" void kernel_launch(void* const* d_in, const int* in_sizes, int n_in,
                              void* d_out, int out_size, void* d_ws, size_t ws_size,
                              hipStream_t stream) {
  const int* input_ids = (const int*)d_in[0];
  const int* output_ids = (const int*)d_in[1];
  const float* enc_emb = (const float*)d_in[2];
  const float* enc_Wih = (const float*)d_in[3];
  const float* enc_Whh = (const float*)d_in[4];
  const float* enc_bih = (const float*)d_in[5];
  const float* enc_bhh = (const float*)d_in[6];
  const float* dec_emb = (const float*)d_in[7];
  const float* dec_Wih = (const float*)d_in[8];
  const float* dec_Whh = (const float*)d_in[9];
  const float* dec_bih = (const float*)d_in[10];
  const float* dec_bhh = (const float*)d_in[11];
  const float* Wout = (const float*)d_in[12];
  const float* bout = (const float*)d_in[13];
  float* out = (float*)d_out;
  char* ws = (char*)d_ws;

  const size_t WL = (size_t)kG * kH;  // per-layer weight stride (elems)

  // ---- workspace layout (bytes) ----
  size_t off = 0;
  // Region A..D: dead after encoder; Wout frags alias here (32.77 MB < 37.75 MB)
  unsigned short* wout_frag = (unsigned short*)(ws + 0);
  unsigned short* xproj_enc = (unsigned short*)(ws + off); off += (size_t)kT * kB * kG * 2;
  unsigned short* xin_enc = (unsigned short*)(ws + off); off += (size_t)kT * kB * kH * 2;
  unsigned short* wih0_enc = (unsigned short*)(ws + off); off += WL * 2;
  unsigned short* wih0_dec = (unsigned short*)(ws + off); off += WL * 2;
  // persistent regions
  unsigned short* xproj_dec = (unsigned short*)(ws + off); off += (size_t)(kT - 1) * kB * kG * 2;
  unsigned short* xin_dec = (unsigned short*)(ws + off); off += (size_t)(kT - 1) * kB * kH * 2;
  unsigned short* htop_frag = xin_dec;  // alias: xin_dec dead before decoder starts
  float* c0 = (float*)(ws + off); off += (size_t)kB * kH * 4;
  float* c1 = (float*)(ws + off); off += (size_t)kB * kH * 4;
  unsigned short* h0swz[2];
  unsigned short* h1swz[2];
  h0swz[0] = (unsigned short*)(ws + off); off += (size_t)kB * kH * 2;
  h0swz[1] = (unsigned short*)(ws + off); off += (size_t)kB * kH * 2;
  h1swz[0] = (unsigned short*)(ws + off); off += (size_t)kB * kH * 2;
  h1swz[1] = (unsigned short*)(ws + off); off += (size_t)kB * kH * 2;
  unsigned short* wswz[6];
  for (int i = 0; i < 6; ++i) { wswz[i] = (unsigned short*)(ws + off); off += WL * 2; }

  // zero c0,c1 + h frag buffers (contiguous)
  hipMemsetAsync(c0, 0, (size_t)kB * kH * (4 + 4 + 2 + 2 + 2 + 2), stream);

  // one-time bf16 fragment-swizzled weight conversions (4096-row mats: 524288 chunks)
  const int wchunks = kG * (kH / 8);  // 524288
  convert_frag<<<2048, 256, 0, stream>>>(enc_Whh, wswz[0], wchunks);
  convert_frag<<<2048, 256, 0, stream>>>(enc_Wih + WL, wswz[1], wchunks);
  convert_frag<<<2048, 256, 0, stream>>>(enc_Whh + WL, wswz[2], wchunks);
  convert_frag<<<2048, 256, 0, stream>>>(dec_Whh, wswz[3], wchunks);
  convert_frag<<<2048, 256, 0, stream>>>(dec_Wih + WL, wswz[4], wchunks);
  convert_frag<<<2048, 256, 0, stream>>>(dec_Whh + WL, wswz[5], wchunks);
  convert_frag<<<2048, 256, 0, stream>>>(enc_Wih, wih0_enc, wchunks);
  convert_frag<<<2048, 256, 0, stream>>>(dec_Wih, wih0_dec, wchunks);

  // gather embeddings into A-frag layout
  gather_frag<<<128 * 8, 256, 0, stream>>>(enc_emb, input_ids, xin_enc, 128);
  gather_frag<<<126 * 8, 256, 0, stream>>>(dec_emb, output_ids, xin_dec, 126);

  // layer-0 input projections (bias fused, bf16 out)
  proj_mfma<<<dim3(32, 32), 256, 0, stream>>>(xin_enc, wih0_enc, enc_bih, enc_bhh,
                                              xproj_enc, 128);
  proj_mfma<<<dim3(32, 32), 256, 0, stream>>>(xin_dec, wih0_dec, dec_bih, dec_bhh,
                                              xproj_dec, 126);

  // ---- recurrence ----
  auto makeL0 = [&](int t) {
    Job j = {};
    j.A1 = h0swz[t & 1];
    j.W1 = (t < kT) ? wswz[0] : wswz[3];
    j.xproj = (t < kT) ? (xproj_enc + (size_t)t * kB * kG)
                       : (xproj_dec + (size_t)(t - kT) * kB * kG);
    j.c = c0;
    j.h_swz = h0swz[(t + 1) & 1];
    return j;
  };
  auto makeL1 = [&](int t) {
    Job j = {};
    j.A0 = h0swz[(t + 1) & 1];
    j.W0 = (t < kT) ? wswz[1] : wswz[4];
    j.A1 = h1swz[t & 1];
    j.W1 = (t < kT) ? wswz[2] : wswz[5];
    j.bih = ((t < kT) ? enc_bih : dec_bih) + kG;
    j.bhh = ((t < kT) ? enc_bhh : dec_bhh) + kG;
    j.c = c1;
    j.h_swz = h1swz[(t + 1) & 1];
    j.h_top = (t >= kT) ? (htop_frag + (size_t)(t - kT) * kB * kH) : nullptr;
    return j;
  };

  constexpr int kSteps = kT + (kT - 1);  // 127
  {
    CellPair P; P.j[0] = makeL0(0); P.j[1] = P.j[0];
    lstm_cells<<<64, 1024, 0, stream>>>(P);
  }
  for (int p = 1; p <= 63; ++p) {
    CellPair P;
    P.j[0] = makeL1(p - 1);
    P.j[1] = makeL0(p);
    lstm_cells<<<128, 1024, 0, stream>>>(P);
  }
  // xproj_enc fully consumed (L0 t=63 ran in p=63) -> build Wout frags in its space
  convert_frag<<<8000, 256, 0, stream>>>(Wout, wout_frag, kV * (kH / 8));
  for (int p = 64; p <= kSteps - 1; ++p) {
    CellPair P;
    P.j[0] = makeL1(p - 1);
    P.j[1] = makeL0(p);
    lstm_cells<<<128, 1024, 0, stream>>>(P);
  }
  {
    CellPair P; P.j[0] = makeL1(kSteps - 1); P.j[1] = P.j[0];
    lstm_cells<<<64, 1024, 0, stream>>>(P);
  }

  // logits[:, 0, :]
  zero_t0_kernel<<<(kB * kV + 255) / 256, 256, 0, stream>>>(out);
  ones_t0_kernel<<<1, kB * kB, 0, stream>>>(output_ids, out);

  // logits[:, 1:, :]
  out_gemm_mfma<<<dim3(32, 125), 256, 0, stream>>>(htop_frag, wout_frag, bout, out);
}